// Round 9
// baseline (317.326 us; speedup 1.0000x reference)
//
#include <hip/hip_runtime.h>
#include <math.h>

#define NUM_EMB 256
#define EMB_DIM 64
#define KSEL 4
#define NBINS 33
#define NSIG 32768          // B*H*W
#define SPB 16              // signals per block (4 waves x 4 signals/wave)
#define NBLK (NSIG / SPB)   // 2048 blocks

// ws layout (bytes):
//   Dn      f32 [64][256]   @ 0        (65536)
//   G       f32 [256][256]  @ 65536    (262144)
//   DnT     f32 [256][64]   @ 327680   (65536)
//   partial f64 [NBLK*4]    @ 393216   (65536)
//   cnt     int             @ 458752
//
// NUMERICS CONTRACT (r4/r5 failures, r1/r2/r3/r6/r8 passes): tokens are
// bit-sensitive to the h_bar formulation. Blessed form: sequential
// ascending-c fp64 FMA chain over f32-rounded Dn values widened in-register
// (r3 exactly). Value-producing expressions below are r3-verbatim; this
// round changes only data MOVEMENT (LDS transpose, DPP reduce, merged y/x,
// fused loss). r6: f64 global loads regress. r7: launch_bounds(256,8)
// spills. r8: block-barrier Dn staging regresses.

template <int CTRL>
__device__ __forceinline__ double dpp_mov_d(double v) {
    union { double d; int i[2]; } u; u.d = v;
    u.i[0] = __builtin_amdgcn_mov_dpp(u.i[0], CTRL, 0xF, 0xF, true);
    u.i[1] = __builtin_amdgcn_mov_dpp(u.i[1], CTRL, 0xF, 0xF, true);
    return u.d;
}
template <int CTRL>
__device__ __forceinline__ int dpp_mov_i(int v) {
    return __builtin_amdgcn_mov_dpp(v, CTRL, 0xF, 0xF, true);
}

__global__ void setup_kernel(const float* __restrict__ dict, float* __restrict__ G,
                             float* __restrict__ Dn, float* __restrict__ DnT,
                             int* __restrict__ cnt) {
    const int t = threadIdx.x;
    if (blockIdx.x == NUM_EMB) {
        if (t == 0) *cnt = 0;   // reset fused-loss counter every call
        double s = 0.0;
        #pragma unroll 8
        for (int c = 0; c < EMB_DIM; ++c) {
            double v = (double)dict[c * NUM_EMB + t];
            s += v * v;
        }
        double inv = 1.0 / fmax(sqrt(s), 1e-10);
        #pragma unroll 8
        for (int c = 0; c < EMB_DIM; ++c) {
            float v = (float)((double)dict[c * NUM_EMB + t] * inv);
            Dn[c * NUM_EMB + t] = v;
            DnT[t * EMB_DIM + c] = v;
        }
        return;
    }
    // gram row a, self-normalizing (bits == r3 gram_kernel)
    const int a = blockIdx.x;
    __shared__ float ca[EMB_DIM];
    if (t < EMB_DIM) {
        double sa = 0.0;
        #pragma unroll 8
        for (int c = 0; c < EMB_DIM; ++c) {
            double v = (double)dict[c * NUM_EMB + a];
            sa += v * v;
        }
        double inva = 1.0 / fmax(sqrt(sa), 1e-10);
        ca[t] = (float)((double)dict[t * NUM_EMB + a] * inva);
    }
    __syncthreads();
    double st = 0.0;
    #pragma unroll 8
    for (int c = 0; c < EMB_DIM; ++c) {
        double v = (double)dict[c * NUM_EMB + t];
        st += v * v;
    }
    double invt = 1.0 / fmax(sqrt(st), 1e-10);
    double s = 0.0;
    #pragma unroll 8
    for (int c = 0; c < EMB_DIM; ++c) {
        float vt = (float)((double)dict[c * NUM_EMB + t] * invt);  // == Dn[c][t] bits
        s += (double)ca[c] * (double)vt;
    }
    G[a * NUM_EMB + t] = (float)s;
}

// 256 threads = 4 independent waves; wave handles 4 signals.
// Phase 2: lane l owns atoms 4l..4l+3 (coalesced float4 Dn rows) — r3 exact.
// Phase 2.5: transpose via per-wave 2KB swizzled LDS scratch (wave-internal
// lgkmcnt sync only). Phase 3: group g -> signal n0+g, lane li owns atoms
// 16li..16li+15; argmax via DPP tree-fold (order-independent selection).
__global__ __launch_bounds__(256, 4)
void omp_kernel(const float* __restrict__ z_e, const float* __restrict__ Dn,
                const float* __restrict__ G, const float* __restrict__ DnT,
                float* __restrict__ out, double* __restrict__ partial,
                int* __restrict__ cnt) {
    __shared__ double zs[4][4][EMB_DIM];            // 8KB
    __shared__ __align__(16) double tsc[4][256];    // 8KB per-wave transpose scratch
    __shared__ int lastflag;
    const int t = threadIdx.x;
    const int w = t >> 6, l = t & 63;
    const int g = l >> 4, li = l & 15;
    const int n0 = blockIdx.x * SPB + w * 4;
    const int b = n0 >> 10, hw0 = n0 & 1023;   // n0 % 4 == 0, same b for 4 signals

    // ---- phase 1: one float4 load: channel=l, signals n0..n0+3 ----
    const float4 zv = *(const float4*)(z_e + (((b * EMB_DIM + l) << 10) + hw0));
    zs[w][0][l] = (double)zv.x;
    zs[w][1][l] = (double)zv.y;
    zs[w][2][l] = (double)zv.z;
    zs[w][3][l] = (double)zv.w;
    asm volatile("s_waitcnt lgkmcnt(0)" ::: "memory"); // wave-wide visibility

    // ---- phase 2: acc[s][r] = h_bar_s[4l+r], fp64, ascending-c FMA chain ----
    double acc[4][4];
    #pragma unroll
    for (int s = 0; s < 4; ++s)
        #pragma unroll
        for (int r = 0; r < 4; ++r) acc[s][r] = 0.0;

    #pragma unroll 4
    for (int c = 0; c < EMB_DIM; c += 2) {
        const float4 dA = *(const float4*)(Dn + c * NUM_EMB + 4 * l);
        const float4 dB = *(const float4*)(Dn + (c + 1) * NUM_EMB + 4 * l);
        double a0 = (double)dA.x, a1 = (double)dA.y, a2 = (double)dA.z, a3 = (double)dA.w;
        double b0 = (double)dB.x, b1 = (double)dB.y, b2 = (double)dB.z, b3 = (double)dB.w;
        #pragma unroll
        for (int s = 0; s < 4; ++s) {
            double2 zp = *(const double2*)&zs[w][s][c];
            acc[s][0] += a0 * zp.x; acc[s][1] += a1 * zp.x;
            acc[s][2] += a2 * zp.x; acc[s][3] += a3 * zp.x;
            acc[s][0] += b0 * zp.y; acc[s][1] += b1 * zp.y;
            acc[s][2] += b2 * zp.y; acc[s][3] += b3 * zp.y;
        }
    }

    // ---- phase 2.5: transpose to phase-3 ownership via swizzled LDS ----
    // write: atom a=4l+r at byte (a*8)^wkey, wkey=((a>>4)&7)<<4=((l>>2)&7)<<4
    // read : atoms 16li+2j at byte (128li+16j)^rkey, rkey=(li&7)<<4
    double hbar[16];
    {
        char* swb = (char*)(tsc[w]);
        const int wkey = ((l >> 2) & 7) << 4;
        const int rkey = (li & 7) << 4;
        #pragma unroll
        for (int sp = 0; sp < 4; ++sp) {
            *(double2*)(swb + ((32 * l) ^ wkey))      = make_double2(acc[sp][0], acc[sp][1]);
            *(double2*)(swb + ((32 * l + 16) ^ wkey)) = make_double2(acc[sp][2], acc[sp][3]);
            asm volatile("s_waitcnt lgkmcnt(0)" ::: "memory");
            if (g == sp) {
                #pragma unroll
                for (int j = 0; j < 8; ++j) {
                    double2 v2 = *(const double2*)(swb + ((128 * li + 16 * j) ^ rkey));
                    hbar[2 * j]     = v2.x;
                    hbar[2 * j + 1] = v2.y;
                }
            }
            asm volatile("s_waitcnt lgkmcnt(0)" ::: "memory");
        }
    }

    // ---- phase 3: OMP, group g -> signal n0+g ----
    int I[KSEL];
    double Lm[KSEL][KSEL], rL[KSEL], hI[KSEL], xy[KSEL];
    unsigned selbits = 0;

    #pragma unroll
    for (int k = 0; k < KSEL; ++k) {
        double bv = -1.0, bh = 0.0; int bi = 0;
        #pragma unroll
        for (int jb = 0; jb < 4; ++jb) {
            double h0 = hbar[4 * jb + 0], h1 = hbar[4 * jb + 1];
            double h2 = hbar[4 * jb + 2], h3 = hbar[4 * jb + 3];
            #pragma unroll
            for (int m = 0; m < k; ++m) {
                const float4 gv = *(const float4*)(G + (I[m] << 8) + 16 * li + 4 * jb);
                h0 -= xy[m] * (double)gv.x;
                h1 -= xy[m] * (double)gv.y;
                h2 -= xy[m] * (double)gv.z;
                h3 -= xy[m] * (double)gv.w;
            }
            #pragma unroll
            for (int r = 0; r < 4; ++r) {
                int j = 4 * jb + r;
                double h = r == 0 ? h0 : r == 1 ? h1 : r == 2 ? h2 : h3;
                double v = ((selbits >> j) & 1u) ? 0.0 : fabs(h);
                if (v > bv) { bv = v; bi = 16 * li + j; bh = hbar[j]; }
            }
        }
        // 16-lane tree-fold (DPP): xor1, xor2 within quads; half-mirror;
        // row-mirror. Total-order selection (max v, tie -> min index) is
        // order-independent -> bit-identical result to the shfl butterfly.
        {
            #define RED_STEP(CTRL) { \
                double ov = dpp_mov_d<CTRL>(bv); \
                double oh = dpp_mov_d<CTRL>(bh); \
                int    oi = dpp_mov_i<CTRL>(bi); \
                if (ov > bv || (ov == bv && oi < bi)) { bv = ov; bi = oi; bh = oh; } }
            RED_STEP(0xB1)   // quad_perm {1,0,3,2}  (xor 1)
            RED_STEP(0x4E)   // quad_perm {2,3,0,1}  (xor 2)
            RED_STEP(0x141)  // row_half_mirror      (cross-quad within 8)
            RED_STEP(0x140)  // row_mirror           (cross-8 within 16)
            #undef RED_STEP
        }
        if ((bi >> 4) == li) selbits |= 1u << (bi & 15);

        // incremental Cholesky (reciprocal diagonals cached) — r3 verbatim
        if (k == 0) {
            Lm[0][0] = 1.0; rL[0] = 1.0;
        } else {
            double wv[KSEL], s2 = 0.0;
            #pragma unroll
            for (int i = 0; i < k; ++i) {
                double v = (double)G[(I[i] << 8) + bi];
                #pragma unroll
                for (int j2 = 0; j2 < i; ++j2) v -= Lm[i][j2] * wv[j2];
                v *= rL[i];
                wv[i] = v; s2 += v * v;
            }
            #pragma unroll
            for (int j2 = 0; j2 < k; ++j2) Lm[k][j2] = wv[j2];
            double dg = sqrt(fmax(1.0 - s2, 1e-12));
            Lm[k][k] = dg; rL[k] = 1.0 / dg;
        }
        I[k]  = bi;
        hI[k] = bh;

        // solve L L^T x = h_bar[I], size k+1, in-place (ops/order == r3)
        #pragma unroll
        for (int i = 0; i <= k; ++i) {
            double v = hI[i];
            #pragma unroll
            for (int j2 = 0; j2 < i; ++j2) v -= Lm[i][j2] * xy[j2];
            xy[i] = v * rL[i];
        }
        #pragma unroll
        for (int i = k; i >= 0; --i) {
            double v = xy[i];
            #pragma unroll
            for (int j2 = i + 1; j2 <= k; ++j2) v -= Lm[j2][i] * xy[j2];
            xy[i] = v * rL[i];
        }
    }

    // ---- phase 4: quantize (fp32, jnp semantics) + tokens ----
    float cq[KSEL]; int tok[KSEL];
    #pragma unroll
    for (int i = 0; i < KSEL; ++i) {
        float xf = (float)xy[i];
        float cc = fminf(fmaxf(xf, -2.0f), 2.0f);
        int bin = (int)rintf((cc + 2.0f) * 8.0f);   // half-to-even, pow2-exact
        bin = bin < 0 ? 0 : (bin > 32 ? 32 : bin);
        cq[i]  = -2.0f + 0.125f * (float)bin;       // CENTERS[bin] exact
        tok[i] = I[i] * NBINS + bin;
    }
    if (li < KSEL) {
        float tv = li == 0 ? (float)tok[0]
                 : li == 1 ? (float)tok[1]
                 : li == 2 ? (float)tok[2] : (float)tok[3];
        out[NSIG * EMB_DIM + 1 + (n0 + g) * KSEL + li] = tv;
    }

    // ---- phase 5: reconstruction (lane=channel, DnT coalesced) + loss ----
    double zq0 = 0.0, zq1 = 0.0, zq2 = 0.0, zq3 = 0.0;
    #pragma unroll
    for (int i = 0; i < KSEL; ++i) {
        int   I0 = __shfl(I[i],  0), I1 = __shfl(I[i], 16);
        int   I2 = __shfl(I[i], 32), I3 = __shfl(I[i], 48);
        float c0 = __shfl(cq[i], 0), c1 = __shfl(cq[i], 16);
        float c2 = __shfl(cq[i], 32), c3 = __shfl(cq[i], 48);
        zq0 += (double)c0 * (double)DnT[(I0 << 6) + l];
        zq1 += (double)c1 * (double)DnT[(I1 << 6) + l];
        zq2 += (double)c2 * (double)DnT[(I2 << 6) + l];
        zq3 += (double)c3 * (double)DnT[(I3 << 6) + l];
    }
    float4 zqv = make_float4((float)zq0, (float)zq1, (float)zq2, (float)zq3);
    *(float4*)(out + (((b * EMB_DIM + l) << 10) + hw0)) = zqv;

    double d0 = (double)zqv.x - zs[w][0][l];
    double d1 = (double)zqv.y - zs[w][1][l];
    double d2 = (double)zqv.z - zs[w][2][l];
    double d3 = (double)zqv.w - zs[w][3][l];
    double sq = d0 * d0 + d1 * d1 + d2 * d2 + d3 * d3;
    #pragma unroll
    for (int off = 1; off < 64; off <<= 1)
        sq += __shfl_xor(sq, off);
    if (l == 0)
        __hip_atomic_store(&partial[blockIdx.x * 4 + w], sq,
                           __ATOMIC_RELEASE, __HIP_MEMORY_SCOPE_AGENT);

    // ---- fused loss: last finished block reduces all partials ----
    __syncthreads();   // all 4 partial stores of this block issued
    if (t == 0) {
        int prev = __hip_atomic_fetch_add(cnt, 1, __ATOMIC_ACQ_REL,
                                          __HIP_MEMORY_SCOPE_AGENT);
        lastflag = (prev == NBLK - 1);
    }
    __syncthreads();
    if (lastflag) {
        double* sh = tsc[0];   // 256 doubles, dead since phase 2.5
        double s = 0.0;
        for (int i = t; i < NBLK * 4; i += 256)
            s += __hip_atomic_load(&partial[i], __ATOMIC_ACQUIRE,
                                   __HIP_MEMORY_SCOPE_AGENT);
        sh[t] = s;
        __syncthreads();
        for (int off = 128; off > 0; off >>= 1) {
            if (t < off) sh[t] += sh[t + off];
            __syncthreads();
        }
        if (t == 0)
            out[NSIG * EMB_DIM] = (float)(1.25 * sh[0] / (double)(NSIG * EMB_DIM));
    }
}

extern "C" void kernel_launch(void* const* d_in, const int* in_sizes, int n_in,
                              void* d_out, int out_size, void* d_ws, size_t ws_size,
                              hipStream_t stream) {
    const float* z_e  = (const float*)d_in[0];
    const float* dict = (const float*)d_in[1];
    float* out = (float*)d_out;

    float*  Dn      = (float*)d_ws;
    float*  G       = (float*)((char*)d_ws + 65536);
    float*  DnT     = (float*)((char*)d_ws + 327680);
    double* partial = (double*)((char*)d_ws + 393216);
    int*    cnt     = (int*)((char*)d_ws + 458752);

    setup_kernel<<<NUM_EMB + 1, 256, 0, stream>>>(dict, G, Dn, DnT, cnt);
    omp_kernel<<<NBLK, 256, 0, stream>>>(z_e, Dn, G, DnT, out, partial, cnt);
}

// Round 10
// 75.477 us; speedup vs baseline: 4.2043x; 4.2043x over previous
//
#include <hip/hip_runtime.h>
#include <math.h>

#define NUM_EMB 256
#define EMB_DIM 64
#define KSEL 4
#define NBINS 33
#define NSIG 32768          // B*H*W
#define SPB 16              // signals per block (4 waves x 4 signals/wave)
#define NBLK (NSIG / SPB)   // 2048 blocks

// ws layout (bytes):
//   Dn      f32 [64][256]   @ 0        (65536)
//   G       f32 [256][256]  @ 65536    (262144)
//   DnT     f32 [256][64]   @ 327680   (65536)
//   partial f64 [NBLK*4]    @ 393216   (65536)
//
// NUMERICS CONTRACT (r4/r5 failures, r1/r2/r3/r6/r8/r9 passes): tokens are
// bit-sensitive to the h_bar formulation. Blessed form: sequential
// ascending-c fp64 FMA chain over f32-rounded Dn values widened in-register
// (r3 exactly). r6: f64 global loads regress. r7: launch_bounds(256,8)
// spills. r8: block-barrier Dn staging regresses. r9: agent-scope
// release/acquire atomics cause L2-flush storms (69->319us) — NEVER fuse
// the loss via device-scope atomics; the extra tiny launch is cheaper.
// r9 keepers (validated): swizzled-LDS transpose (bank conflicts 2.1M->0),
// DPP argmax, in-place solve.

template <int CTRL>
__device__ __forceinline__ double dpp_mov_d(double v) {
    union { double d; int i[2]; } u; u.d = v;
    u.i[0] = __builtin_amdgcn_mov_dpp(u.i[0], CTRL, 0xF, 0xF, true);
    u.i[1] = __builtin_amdgcn_mov_dpp(u.i[1], CTRL, 0xF, 0xF, true);
    return u.d;
}
template <int CTRL>
__device__ __forceinline__ int dpp_mov_i(int v) {
    return __builtin_amdgcn_mov_dpp(v, CTRL, 0xF, 0xF, true);
}

__global__ void setup_kernel(const float* __restrict__ dict, float* __restrict__ G,
                             float* __restrict__ Dn, float* __restrict__ DnT) {
    const int t = threadIdx.x;
    if (blockIdx.x == NUM_EMB) {
        double s = 0.0;
        #pragma unroll 8
        for (int c = 0; c < EMB_DIM; ++c) {
            double v = (double)dict[c * NUM_EMB + t];
            s += v * v;
        }
        double inv = 1.0 / fmax(sqrt(s), 1e-10);
        #pragma unroll 8
        for (int c = 0; c < EMB_DIM; ++c) {
            float v = (float)((double)dict[c * NUM_EMB + t] * inv);
            Dn[c * NUM_EMB + t] = v;
            DnT[t * EMB_DIM + c] = v;
        }
        return;
    }
    // gram row a, self-normalizing (bits == r3 gram_kernel)
    const int a = blockIdx.x;
    __shared__ float ca[EMB_DIM];
    if (t < EMB_DIM) {
        double sa = 0.0;
        #pragma unroll 8
        for (int c = 0; c < EMB_DIM; ++c) {
            double v = (double)dict[c * NUM_EMB + a];
            sa += v * v;
        }
        double inva = 1.0 / fmax(sqrt(sa), 1e-10);
        ca[t] = (float)((double)dict[t * NUM_EMB + a] * inva);
    }
    __syncthreads();
    double st = 0.0;
    #pragma unroll 8
    for (int c = 0; c < EMB_DIM; ++c) {
        double v = (double)dict[c * NUM_EMB + t];
        st += v * v;
    }
    double invt = 1.0 / fmax(sqrt(st), 1e-10);
    double s = 0.0;
    #pragma unroll 8
    for (int c = 0; c < EMB_DIM; ++c) {
        float vt = (float)((double)dict[c * NUM_EMB + t] * invt);  // == Dn[c][t] bits
        s += (double)ca[c] * (double)vt;
    }
    G[a * NUM_EMB + t] = (float)s;
}

// 256 threads = 4 independent waves; wave handles 4 signals.
// Phase 2: lane l owns atoms 4l..4l+3 (coalesced float4 Dn rows) — r3 exact.
// Phase 2.5: transpose via per-wave 2KB swizzled LDS scratch (wave-internal
// lgkmcnt sync only). Phase 3: group g -> signal n0+g, lane li owns atoms
// 16li..16li+15; argmax via DPP tree-fold (order-independent selection).
__global__ __launch_bounds__(256, 4)
void omp_kernel(const float* __restrict__ z_e, const float* __restrict__ Dn,
                const float* __restrict__ G, const float* __restrict__ DnT,
                float* __restrict__ out, double* __restrict__ partial) {
    __shared__ double zs[4][4][EMB_DIM];            // 8KB
    __shared__ __align__(16) double tsc[4][256];    // 8KB per-wave transpose scratch
    const int t = threadIdx.x;
    const int w = t >> 6, l = t & 63;
    const int g = l >> 4, li = l & 15;
    const int n0 = blockIdx.x * SPB + w * 4;
    const int b = n0 >> 10, hw0 = n0 & 1023;   // n0 % 4 == 0, same b for 4 signals

    // ---- phase 1: one float4 load: channel=l, signals n0..n0+3 ----
    const float4 zv = *(const float4*)(z_e + (((b * EMB_DIM + l) << 10) + hw0));
    zs[w][0][l] = (double)zv.x;
    zs[w][1][l] = (double)zv.y;
    zs[w][2][l] = (double)zv.z;
    zs[w][3][l] = (double)zv.w;
    asm volatile("s_waitcnt lgkmcnt(0)" ::: "memory"); // wave-wide visibility

    // ---- phase 2: acc[s][r] = h_bar_s[4l+r], fp64, ascending-c FMA chain ----
    double acc[4][4];
    #pragma unroll
    for (int s = 0; s < 4; ++s)
        #pragma unroll
        for (int r = 0; r < 4; ++r) acc[s][r] = 0.0;

    #pragma unroll 4
    for (int c = 0; c < EMB_DIM; c += 2) {
        const float4 dA = *(const float4*)(Dn + c * NUM_EMB + 4 * l);
        const float4 dB = *(const float4*)(Dn + (c + 1) * NUM_EMB + 4 * l);
        double a0 = (double)dA.x, a1 = (double)dA.y, a2 = (double)dA.z, a3 = (double)dA.w;
        double b0 = (double)dB.x, b1 = (double)dB.y, b2 = (double)dB.z, b3 = (double)dB.w;
        #pragma unroll
        for (int s = 0; s < 4; ++s) {
            double2 zp = *(const double2*)&zs[w][s][c];
            acc[s][0] += a0 * zp.x; acc[s][1] += a1 * zp.x;
            acc[s][2] += a2 * zp.x; acc[s][3] += a3 * zp.x;
            acc[s][0] += b0 * zp.y; acc[s][1] += b1 * zp.y;
            acc[s][2] += b2 * zp.y; acc[s][3] += b3 * zp.y;
        }
    }

    // ---- phase 2.5: transpose to phase-3 ownership via swizzled LDS ----
    // write: atom a=4l+r at byte (a*8)^wkey, wkey=((a>>4)&7)<<4=((l>>2)&7)<<4
    // read : atoms 16li+2j at byte (128li+16j)^rkey, rkey=(li&7)<<4
    double hbar[16];
    {
        char* swb = (char*)(tsc[w]);
        const int wkey = ((l >> 2) & 7) << 4;
        const int rkey = (li & 7) << 4;
        #pragma unroll
        for (int sp = 0; sp < 4; ++sp) {
            *(double2*)(swb + ((32 * l) ^ wkey))      = make_double2(acc[sp][0], acc[sp][1]);
            *(double2*)(swb + ((32 * l + 16) ^ wkey)) = make_double2(acc[sp][2], acc[sp][3]);
            asm volatile("s_waitcnt lgkmcnt(0)" ::: "memory");
            if (g == sp) {
                #pragma unroll
                for (int j = 0; j < 8; ++j) {
                    double2 v2 = *(const double2*)(swb + ((128 * li + 16 * j) ^ rkey));
                    hbar[2 * j]     = v2.x;
                    hbar[2 * j + 1] = v2.y;
                }
            }
            asm volatile("s_waitcnt lgkmcnt(0)" ::: "memory");
        }
    }

    // ---- phase 3: OMP, group g -> signal n0+g ----
    int I[KSEL];
    double Lm[KSEL][KSEL], rL[KSEL], hI[KSEL], xy[KSEL];
    unsigned selbits = 0;

    #pragma unroll
    for (int k = 0; k < KSEL; ++k) {
        double bv = -1.0, bh = 0.0; int bi = 0;
        #pragma unroll
        for (int jb = 0; jb < 4; ++jb) {
            double h0 = hbar[4 * jb + 0], h1 = hbar[4 * jb + 1];
            double h2 = hbar[4 * jb + 2], h3 = hbar[4 * jb + 3];
            #pragma unroll
            for (int m = 0; m < k; ++m) {
                const float4 gv = *(const float4*)(G + (I[m] << 8) + 16 * li + 4 * jb);
                h0 -= xy[m] * (double)gv.x;
                h1 -= xy[m] * (double)gv.y;
                h2 -= xy[m] * (double)gv.z;
                h3 -= xy[m] * (double)gv.w;
            }
            #pragma unroll
            for (int r = 0; r < 4; ++r) {
                int j = 4 * jb + r;
                double h = r == 0 ? h0 : r == 1 ? h1 : r == 2 ? h2 : h3;
                double v = ((selbits >> j) & 1u) ? 0.0 : fabs(h);
                if (v > bv) { bv = v; bi = 16 * li + j; bh = hbar[j]; }
            }
        }
        // 16-lane tree-fold (DPP): xor1, xor2 within quads; half-mirror;
        // row-mirror. Total-order selection (max v, tie -> min index) is
        // order-independent -> identical result to the shfl butterfly.
        {
            #define RED_STEP(CTRL) { \
                double ov = dpp_mov_d<CTRL>(bv); \
                double oh = dpp_mov_d<CTRL>(bh); \
                int    oi = dpp_mov_i<CTRL>(bi); \
                if (ov > bv || (ov == bv && oi < bi)) { bv = ov; bi = oi; bh = oh; } }
            RED_STEP(0xB1)   // quad_perm {1,0,3,2}  (xor 1)
            RED_STEP(0x4E)   // quad_perm {2,3,0,1}  (xor 2)
            RED_STEP(0x141)  // row_half_mirror      (cross-quad within 8)
            RED_STEP(0x140)  // row_mirror           (cross-8 within 16)
            #undef RED_STEP
        }
        if ((bi >> 4) == li) selbits |= 1u << (bi & 15);

        // incremental Cholesky (reciprocal diagonals cached) — r3 verbatim
        if (k == 0) {
            Lm[0][0] = 1.0; rL[0] = 1.0;
        } else {
            double wv[KSEL], s2 = 0.0;
            #pragma unroll
            for (int i = 0; i < k; ++i) {
                double v = (double)G[(I[i] << 8) + bi];
                #pragma unroll
                for (int j2 = 0; j2 < i; ++j2) v -= Lm[i][j2] * wv[j2];
                v *= rL[i];
                wv[i] = v; s2 += v * v;
            }
            #pragma unroll
            for (int j2 = 0; j2 < k; ++j2) Lm[k][j2] = wv[j2];
            double dg = sqrt(fmax(1.0 - s2, 1e-12));
            Lm[k][k] = dg; rL[k] = 1.0 / dg;
        }
        I[k]  = bi;
        hI[k] = bh;

        // solve L L^T x = h_bar[I], size k+1, in-place (ops/order == r3)
        #pragma unroll
        for (int i = 0; i <= k; ++i) {
            double v = hI[i];
            #pragma unroll
            for (int j2 = 0; j2 < i; ++j2) v -= Lm[i][j2] * xy[j2];
            xy[i] = v * rL[i];
        }
        #pragma unroll
        for (int i = k; i >= 0; --i) {
            double v = xy[i];
            #pragma unroll
            for (int j2 = i + 1; j2 <= k; ++j2) v -= Lm[j2][i] * xy[j2];
            xy[i] = v * rL[i];
        }
    }

    // ---- phase 4: quantize (fp32, jnp semantics) + tokens ----
    float cq[KSEL]; int tok[KSEL];
    #pragma unroll
    for (int i = 0; i < KSEL; ++i) {
        float xf = (float)xy[i];
        float cc = fminf(fmaxf(xf, -2.0f), 2.0f);
        int bin = (int)rintf((cc + 2.0f) * 8.0f);   // half-to-even, pow2-exact
        bin = bin < 0 ? 0 : (bin > 32 ? 32 : bin);
        cq[i]  = -2.0f + 0.125f * (float)bin;       // CENTERS[bin] exact
        tok[i] = I[i] * NBINS + bin;
    }
    if (li < KSEL) {
        float tv = li == 0 ? (float)tok[0]
                 : li == 1 ? (float)tok[1]
                 : li == 2 ? (float)tok[2] : (float)tok[3];
        out[NSIG * EMB_DIM + 1 + (n0 + g) * KSEL + li] = tv;
    }

    // ---- phase 5: reconstruction (lane=channel, DnT coalesced) + loss ----
    double zq0 = 0.0, zq1 = 0.0, zq2 = 0.0, zq3 = 0.0;
    #pragma unroll
    for (int i = 0; i < KSEL; ++i) {
        int   I0 = __shfl(I[i],  0), I1 = __shfl(I[i], 16);
        int   I2 = __shfl(I[i], 32), I3 = __shfl(I[i], 48);
        float c0 = __shfl(cq[i], 0), c1 = __shfl(cq[i], 16);
        float c2 = __shfl(cq[i], 32), c3 = __shfl(cq[i], 48);
        zq0 += (double)c0 * (double)DnT[(I0 << 6) + l];
        zq1 += (double)c1 * (double)DnT[(I1 << 6) + l];
        zq2 += (double)c2 * (double)DnT[(I2 << 6) + l];
        zq3 += (double)c3 * (double)DnT[(I3 << 6) + l];
    }
    float4 zqv = make_float4((float)zq0, (float)zq1, (float)zq2, (float)zq3);
    *(float4*)(out + (((b * EMB_DIM + l) << 10) + hw0)) = zqv;

    double d0 = (double)zqv.x - zs[w][0][l];
    double d1 = (double)zqv.y - zs[w][1][l];
    double d2 = (double)zqv.z - zs[w][2][l];
    double d3 = (double)zqv.w - zs[w][3][l];
    double sq = d0 * d0 + d1 * d1 + d2 * d2 + d3 * d3;
    #pragma unroll
    for (int off = 1; off < 64; off <<= 1)
        sq += __shfl_xor(sq, off);
    if (l == 0) partial[blockIdx.x * 4 + w] = sq;
}

__global__ void loss_kernel(const double* __restrict__ partial, float* __restrict__ out) {
    __shared__ double sh[256];
    int t = threadIdx.x;
    double s = 0.0;
    for (int i = t; i < NBLK * 4; i += 256) s += partial[i];
    sh[t] = s;
    __syncthreads();
    for (int off = 128; off > 0; off >>= 1) {
        if (t < off) sh[t] += sh[t + off];
        __syncthreads();
    }
    if (t == 0)
        out[NSIG * EMB_DIM] = (float)(1.25 * sh[0] / (double)(NSIG * EMB_DIM));
}

extern "C" void kernel_launch(void* const* d_in, const int* in_sizes, int n_in,
                              void* d_out, int out_size, void* d_ws, size_t ws_size,
                              hipStream_t stream) {
    const float* z_e  = (const float*)d_in[0];
    const float* dict = (const float*)d_in[1];
    float* out = (float*)d_out;

    float*  Dn      = (float*)d_ws;
    float*  G       = (float*)((char*)d_ws + 65536);
    float*  DnT     = (float*)((char*)d_ws + 327680);
    double* partial = (double*)((char*)d_ws + 393216);

    setup_kernel<<<NUM_EMB + 1, 256, 0, stream>>>(dict, G, Dn, DnT);
    omp_kernel<<<NBLK, 256, 0, stream>>>(z_e, Dn, G, DnT, out, partial);
    loss_kernel<<<1, 256, 0, stream>>>(partial, out);
}

// Round 11
// 74.495 us; speedup vs baseline: 4.2597x; 1.0132x over previous
//
#include <hip/hip_runtime.h>
#include <math.h>

#define NUM_EMB 256
#define EMB_DIM 64
#define KSEL 4
#define NBINS 33
#define NSIG 32768          // B*H*W
#define SPB 16              // signals per block (4 waves x 4 signals/wave)
#define NBLK (NSIG / SPB)   // 2048 blocks

// ws layout (bytes):
//   Dn      f32 [64][256]   @ 0        (65536)
//   G       f32 [256][256]  @ 65536    (262144)
//   DnT     f32 [256][64]   @ 327680   (65536)
//   partial f64 [NBLK*4]    @ 393216   (65536)
//
// NUMERICS CONTRACT (r4/r5 failures; r1/r2/r3/r6/r8/r9/r10 passes): tokens
// are bit-sensitive to the h_bar formulation. Blessed form: sequential
// ascending-c fp64 FMA chain over f32-rounded Dn values widened in-register
// (r3 exactly). r6: f64 global loads regress. r7: launch_bounds(256,8)
// forces VGPR=32 + spills (151us). r8: block-barrier Dn staging regresses.
// r9: agent-scope release/acquire atomics cause L2-flush storms (319us).
// r10 keepers: swizzled-LDS transpose (bank conflicts 2.1M->0), DPP argmax,
// in-place solve. THIS ROUND (single variable): drop the ",4" from
// launch_bounds — r1 evidence says the 2nd arg caps resident waves/EU.

template <int CTRL>
__device__ __forceinline__ double dpp_mov_d(double v) {
    union { double d; int i[2]; } u; u.d = v;
    u.i[0] = __builtin_amdgcn_mov_dpp(u.i[0], CTRL, 0xF, 0xF, true);
    u.i[1] = __builtin_amdgcn_mov_dpp(u.i[1], CTRL, 0xF, 0xF, true);
    return u.d;
}
template <int CTRL>
__device__ __forceinline__ int dpp_mov_i(int v) {
    return __builtin_amdgcn_mov_dpp(v, CTRL, 0xF, 0xF, true);
}

__global__ void setup_kernel(const float* __restrict__ dict, float* __restrict__ G,
                             float* __restrict__ Dn, float* __restrict__ DnT) {
    const int t = threadIdx.x;
    if (blockIdx.x == NUM_EMB) {
        double s = 0.0;
        #pragma unroll 8
        for (int c = 0; c < EMB_DIM; ++c) {
            double v = (double)dict[c * NUM_EMB + t];
            s += v * v;
        }
        double inv = 1.0 / fmax(sqrt(s), 1e-10);
        #pragma unroll 8
        for (int c = 0; c < EMB_DIM; ++c) {
            float v = (float)((double)dict[c * NUM_EMB + t] * inv);
            Dn[c * NUM_EMB + t] = v;
            DnT[t * EMB_DIM + c] = v;
        }
        return;
    }
    // gram row a, self-normalizing (bits == r3 gram_kernel)
    const int a = blockIdx.x;
    __shared__ float ca[EMB_DIM];
    if (t < EMB_DIM) {
        double sa = 0.0;
        #pragma unroll 8
        for (int c = 0; c < EMB_DIM; ++c) {
            double v = (double)dict[c * NUM_EMB + a];
            sa += v * v;
        }
        double inva = 1.0 / fmax(sqrt(sa), 1e-10);
        ca[t] = (float)((double)dict[t * NUM_EMB + a] * inva);
    }
    __syncthreads();
    double st = 0.0;
    #pragma unroll 8
    for (int c = 0; c < EMB_DIM; ++c) {
        double v = (double)dict[c * NUM_EMB + t];
        st += v * v;
    }
    double invt = 1.0 / fmax(sqrt(st), 1e-10);
    double s = 0.0;
    #pragma unroll 8
    for (int c = 0; c < EMB_DIM; ++c) {
        float vt = (float)((double)dict[c * NUM_EMB + t] * invt);  // == Dn[c][t] bits
        s += (double)ca[c] * (double)vt;
    }
    G[a * NUM_EMB + t] = (float)s;
}

// 256 threads = 4 independent waves; wave handles 4 signals.
// Phase 2: lane l owns atoms 4l..4l+3 (coalesced float4 Dn rows) — r3 exact.
// Phase 2.5: transpose via per-wave 2KB swizzled LDS scratch (wave-internal
// lgkmcnt sync only). Phase 3: group g -> signal n0+g, lane li owns atoms
// 16li..16li+15; argmax via DPP tree-fold (order-independent selection).
__global__ __launch_bounds__(256)
void omp_kernel(const float* __restrict__ z_e, const float* __restrict__ Dn,
                const float* __restrict__ G, const float* __restrict__ DnT,
                float* __restrict__ out, double* __restrict__ partial) {
    __shared__ double zs[4][4][EMB_DIM];            // 8KB
    __shared__ __align__(16) double tsc[4][256];    // 8KB per-wave transpose scratch
    const int t = threadIdx.x;
    const int w = t >> 6, l = t & 63;
    const int g = l >> 4, li = l & 15;
    const int n0 = blockIdx.x * SPB + w * 4;
    const int b = n0 >> 10, hw0 = n0 & 1023;   // n0 % 4 == 0, same b for 4 signals

    // ---- phase 1: one float4 load: channel=l, signals n0..n0+3 ----
    const float4 zv = *(const float4*)(z_e + (((b * EMB_DIM + l) << 10) + hw0));
    zs[w][0][l] = (double)zv.x;
    zs[w][1][l] = (double)zv.y;
    zs[w][2][l] = (double)zv.z;
    zs[w][3][l] = (double)zv.w;
    asm volatile("s_waitcnt lgkmcnt(0)" ::: "memory"); // wave-wide visibility

    // ---- phase 2: acc[s][r] = h_bar_s[4l+r], fp64, ascending-c FMA chain ----
    double acc[4][4];
    #pragma unroll
    for (int s = 0; s < 4; ++s)
        #pragma unroll
        for (int r = 0; r < 4; ++r) acc[s][r] = 0.0;

    #pragma unroll 4
    for (int c = 0; c < EMB_DIM; c += 2) {
        const float4 dA = *(const float4*)(Dn + c * NUM_EMB + 4 * l);
        const float4 dB = *(const float4*)(Dn + (c + 1) * NUM_EMB + 4 * l);
        double a0 = (double)dA.x, a1 = (double)dA.y, a2 = (double)dA.z, a3 = (double)dA.w;
        double b0 = (double)dB.x, b1 = (double)dB.y, b2 = (double)dB.z, b3 = (double)dB.w;
        #pragma unroll
        for (int s = 0; s < 4; ++s) {
            double2 zp = *(const double2*)&zs[w][s][c];
            acc[s][0] += a0 * zp.x; acc[s][1] += a1 * zp.x;
            acc[s][2] += a2 * zp.x; acc[s][3] += a3 * zp.x;
            acc[s][0] += b0 * zp.y; acc[s][1] += b1 * zp.y;
            acc[s][2] += b2 * zp.y; acc[s][3] += b3 * zp.y;
        }
    }

    // ---- phase 2.5: transpose to phase-3 ownership via swizzled LDS ----
    // write: atom a=4l+r at byte (a*8)^wkey, wkey=((a>>4)&7)<<4=((l>>2)&7)<<4
    // read : atoms 16li+2j at byte (128li+16j)^rkey, rkey=(li&7)<<4
    double hbar[16];
    {
        char* swb = (char*)(tsc[w]);
        const int wkey = ((l >> 2) & 7) << 4;
        const int rkey = (li & 7) << 4;
        #pragma unroll
        for (int sp = 0; sp < 4; ++sp) {
            *(double2*)(swb + ((32 * l) ^ wkey))      = make_double2(acc[sp][0], acc[sp][1]);
            *(double2*)(swb + ((32 * l + 16) ^ wkey)) = make_double2(acc[sp][2], acc[sp][3]);
            asm volatile("s_waitcnt lgkmcnt(0)" ::: "memory");
            if (g == sp) {
                #pragma unroll
                for (int j = 0; j < 8; ++j) {
                    double2 v2 = *(const double2*)(swb + ((128 * li + 16 * j) ^ rkey));
                    hbar[2 * j]     = v2.x;
                    hbar[2 * j + 1] = v2.y;
                }
            }
            asm volatile("s_waitcnt lgkmcnt(0)" ::: "memory");
        }
    }

    // ---- phase 3: OMP, group g -> signal n0+g ----
    int I[KSEL];
    double Lm[KSEL][KSEL], rL[KSEL], hI[KSEL], xy[KSEL];
    unsigned selbits = 0;

    #pragma unroll
    for (int k = 0; k < KSEL; ++k) {
        double bv = -1.0, bh = 0.0; int bi = 0;
        #pragma unroll
        for (int jb = 0; jb < 4; ++jb) {
            double h0 = hbar[4 * jb + 0], h1 = hbar[4 * jb + 1];
            double h2 = hbar[4 * jb + 2], h3 = hbar[4 * jb + 3];
            #pragma unroll
            for (int m = 0; m < k; ++m) {
                const float4 gv = *(const float4*)(G + (I[m] << 8) + 16 * li + 4 * jb);
                h0 -= xy[m] * (double)gv.x;
                h1 -= xy[m] * (double)gv.y;
                h2 -= xy[m] * (double)gv.z;
                h3 -= xy[m] * (double)gv.w;
            }
            #pragma unroll
            for (int r = 0; r < 4; ++r) {
                int j = 4 * jb + r;
                double h = r == 0 ? h0 : r == 1 ? h1 : r == 2 ? h2 : h3;
                double v = ((selbits >> j) & 1u) ? 0.0 : fabs(h);
                if (v > bv) { bv = v; bi = 16 * li + j; bh = hbar[j]; }
            }
        }
        // 16-lane tree-fold (DPP): xor1, xor2 within quads; half-mirror;
        // row-mirror. Total-order selection (max v, tie -> min index) is
        // order-independent -> identical result to the shfl butterfly.
        {
            #define RED_STEP(CTRL) { \
                double ov = dpp_mov_d<CTRL>(bv); \
                double oh = dpp_mov_d<CTRL>(bh); \
                int    oi = dpp_mov_i<CTRL>(bi); \
                if (ov > bv || (ov == bv && oi < bi)) { bv = ov; bi = oi; bh = oh; } }
            RED_STEP(0xB1)   // quad_perm {1,0,3,2}  (xor 1)
            RED_STEP(0x4E)   // quad_perm {2,3,0,1}  (xor 2)
            RED_STEP(0x141)  // row_half_mirror      (cross-quad within 8)
            RED_STEP(0x140)  // row_mirror           (cross-8 within 16)
            #undef RED_STEP
        }
        if ((bi >> 4) == li) selbits |= 1u << (bi & 15);

        // incremental Cholesky (reciprocal diagonals cached) — r3 verbatim
        if (k == 0) {
            Lm[0][0] = 1.0; rL[0] = 1.0;
        } else {
            double wv[KSEL], s2 = 0.0;
            #pragma unroll
            for (int i = 0; i < k; ++i) {
                double v = (double)G[(I[i] << 8) + bi];
                #pragma unroll
                for (int j2 = 0; j2 < i; ++j2) v -= Lm[i][j2] * wv[j2];
                v *= rL[i];
                wv[i] = v; s2 += v * v;
            }
            #pragma unroll
            for (int j2 = 0; j2 < k; ++j2) Lm[k][j2] = wv[j2];
            double dg = sqrt(fmax(1.0 - s2, 1e-12));
            Lm[k][k] = dg; rL[k] = 1.0 / dg;
        }
        I[k]  = bi;
        hI[k] = bh;

        // solve L L^T x = h_bar[I], size k+1, in-place (ops/order == r3)
        #pragma unroll
        for (int i = 0; i <= k; ++i) {
            double v = hI[i];
            #pragma unroll
            for (int j2 = 0; j2 < i; ++j2) v -= Lm[i][j2] * xy[j2];
            xy[i] = v * rL[i];
        }
        #pragma unroll
        for (int i = k; i >= 0; --i) {
            double v = xy[i];
            #pragma unroll
            for (int j2 = i + 1; j2 <= k; ++j2) v -= Lm[j2][i] * xy[j2];
            xy[i] = v * rL[i];
        }
    }

    // ---- phase 4: quantize (fp32, jnp semantics) + tokens ----
    float cq[KSEL]; int tok[KSEL];
    #pragma unroll
    for (int i = 0; i < KSEL; ++i) {
        float xf = (float)xy[i];
        float cc = fminf(fmaxf(xf, -2.0f), 2.0f);
        int bin = (int)rintf((cc + 2.0f) * 8.0f);   // half-to-even, pow2-exact
        bin = bin < 0 ? 0 : (bin > 32 ? 32 : bin);
        cq[i]  = -2.0f + 0.125f * (float)bin;       // CENTERS[bin] exact
        tok[i] = I[i] * NBINS + bin;
    }
    if (li < KSEL) {
        float tv = li == 0 ? (float)tok[0]
                 : li == 1 ? (float)tok[1]
                 : li == 2 ? (float)tok[2] : (float)tok[3];
        out[NSIG * EMB_DIM + 1 + (n0 + g) * KSEL + li] = tv;
    }

    // ---- phase 5: reconstruction (lane=channel, DnT coalesced) + loss ----
    double zq0 = 0.0, zq1 = 0.0, zq2 = 0.0, zq3 = 0.0;
    #pragma unroll
    for (int i = 0; i < KSEL; ++i) {
        int   I0 = __shfl(I[i],  0), I1 = __shfl(I[i], 16);
        int   I2 = __shfl(I[i], 32), I3 = __shfl(I[i], 48);
        float c0 = __shfl(cq[i], 0), c1 = __shfl(cq[i], 16);
        float c2 = __shfl(cq[i], 32), c3 = __shfl(cq[i], 48);
        zq0 += (double)c0 * (double)DnT[(I0 << 6) + l];
        zq1 += (double)c1 * (double)DnT[(I1 << 6) + l];
        zq2 += (double)c2 * (double)DnT[(I2 << 6) + l];
        zq3 += (double)c3 * (double)DnT[(I3 << 6) + l];
    }
    float4 zqv = make_float4((float)zq0, (float)zq1, (float)zq2, (float)zq3);
    *(float4*)(out + (((b * EMB_DIM + l) << 10) + hw0)) = zqv;

    double d0 = (double)zqv.x - zs[w][0][l];
    double d1 = (double)zqv.y - zs[w][1][l];
    double d2 = (double)zqv.z - zs[w][2][l];
    double d3 = (double)zqv.w - zs[w][3][l];
    double sq = d0 * d0 + d1 * d1 + d2 * d2 + d3 * d3;
    #pragma unroll
    for (int off = 1; off < 64; off <<= 1)
        sq += __shfl_xor(sq, off);
    if (l == 0) partial[blockIdx.x * 4 + w] = sq;
}

__global__ void loss_kernel(const double* __restrict__ partial, float* __restrict__ out) {
    __shared__ double sh[256];
    int t = threadIdx.x;
    double s = 0.0;
    for (int i = t; i < NBLK * 4; i += 256) s += partial[i];
    sh[t] = s;
    __syncthreads();
    for (int off = 128; off > 0; off >>= 1) {
        if (t < off) sh[t] += sh[t + off];
        __syncthreads();
    }
    if (t == 0)
        out[NSIG * EMB_DIM] = (float)(1.25 * sh[0] / (double)(NSIG * EMB_DIM));
}

extern "C" void kernel_launch(void* const* d_in, const int* in_sizes, int n_in,
                              void* d_out, int out_size, void* d_ws, size_t ws_size,
                              hipStream_t stream) {
    const float* z_e  = (const float*)d_in[0];
    const float* dict = (const float*)d_in[1];
    float* out = (float*)d_out;

    float*  Dn      = (float*)d_ws;
    float*  G       = (float*)((char*)d_ws + 65536);
    float*  DnT     = (float*)((char*)d_ws + 327680);
    double* partial = (double*)((char*)d_ws + 393216);

    setup_kernel<<<NUM_EMB + 1, 256, 0, stream>>>(dict, G, Dn, DnT);
    omp_kernel<<<NBLK, 256, 0, stream>>>(z_e, Dn, G, DnT, out, partial);
    loss_kernel<<<1, 256, 0, stream>>>(partial, out);
}